// Round 2
// baseline (331.128 us; speedup 1.0000x reference)
//
#include <hip/hip_runtime.h>

// RoIAlign forward, MI355X.
// Shapes: features (4,256,200,200) fp32 NCHW, rois (512,5) fp32,
// out (512,256,7,7) fp32. OUT 7x7, sampling S=2, scale 0.25.
//
// Round-2 restructure: batched single-round-trip staging.
//  - block = (roi, 8-channel chunk); grid 512*32.
//  - Footprint bound (tight): roi_w = max((x2-x1)*0.25,1) <= 24 feat px;
//    sample span = 6.5*bin = 0.9286*roi_w <= 22.29; fw = floor(lo+span)+1
//    - floor(lo) + 1 <= 23 + 2 = 25. Same for fh. MAXF = 25.
//  - Staging: thread = (c = tid&7, row ys = tid>>3). Each thread loads its
//    whole row as <=7 aligned float4 (x aligned down to mult of 4; extent
//    <= 25+3 = 28 -> 7 segs), statically unrolled + predicated. ALL loads
//    issue before one waitcnt -> ONE memory round trip per block (vs ~10
//    serial in round 1 -- which is why 2.3x occupancy bought nothing).
//  - LDS: channel planes, stride PLSTR=700 floats (25 rows * 28).
//    700 % 32 = 28 -> 8 cl-lanes hit distinct banks on compute reads;
//    700 % 4 = 0 -> 16B-aligned ds_write_b128. Tile 22.4 KB -> 6-7 blk/CU.
//  - Compute: thread = (cl = tid&7, slot = tid>>3); bins slot, slot+32.

#define OH 7
#define OW 7
#define NSAMP 14          // OH*2 == OW*2
#define CH 256
#define FH 200
#define FW 200
#define NR 512
#define CCH 8             // channels per chunk
#define NCHUNK (CH / CCH) // 32
#define MAXF 25           // max footprint extent (proven bound)
#define MAXSEG 7          // max float4 segments per row (extent<=28)
#define PLSTR 700         // plane stride, floats (25 * 28); %32=28, %4=0
#define BLK 256

__global__ __launch_bounds__(BLK) void roialign_fwd(
    const float* __restrict__ feat,
    const float* __restrict__ rois,
    float* __restrict__ out)
{
    __shared__ float tile[CCH * PLSTR];       // 22.4 KB channel planes
    __shared__ int   s_il[2][NSAMP];          // axis 0 = y, 1 = x
    __shared__ int   s_ih[2][NSAMP];
    __shared__ float s_w0[2][NSAMP];
    __shared__ float s_w1[2][NSAMP];

    const int block = blockIdx.x;
    const int r     = block >> 5;             // roi index
    const int chunk = block & (NCHUNK - 1);
    const int c0    = chunk * CCH;
    const int tid   = threadIdx.x;

    // ---- ROI params (wave-uniform scalar loads) ----
    const int   b  = (int)rois[r * 5 + 0];
    const float x1 = rois[r * 5 + 1] * 0.25f;
    const float y1 = rois[r * 5 + 2] * 0.25f;
    const float x2 = rois[r * 5 + 3] * 0.25f;
    const float y2 = rois[r * 5 + 4] * 0.25f;
    const float roi_w = fmaxf(x2 - x1, 1.0f);
    const float roi_h = fmaxf(y2 - y1, 1.0f);
    const float bw = roi_w * (1.0f / OW);
    const float bh = roi_h * (1.0f / OH);

    // ---- per-axis sample metadata (matches reference _axis_weights) ----
    if (tid < 2 * NSAMP) {
        const int axis = tid >= NSAMP;        // 0 = y, 1 = x
        const int i    = tid - axis * NSAMP;
        const float start = axis ? x1 : y1;
        const float bsz   = axis ? bw : bh;
        const float pos   = start + (i + 0.5f) * 0.5f * bsz;
        const float valid = (pos >= -1.0f && pos <= 200.0f) ? 1.0f : 0.0f;
        const float pc    = fminf(fmaxf(pos, 0.0f), 199.0f);
        const int   il    = (int)floorf(pc);
        const int   ih    = min(il + 1, 199);
        const float l     = pc - (float)il;
        s_il[axis][i] = il;
        s_ih[axis][i] = ih;
        s_w0[axis][i] = (1.0f - l) * valid;
        s_w1[axis][i] = l * valid;
    }
    __syncthreads();

    // footprint bounds (sample coords monotone in i)
    const int ylo = s_il[0][0];
    const int xlo = s_il[1][0];
    const int fh = min(s_ih[0][NSAMP - 1] - ylo + 1, MAXF);
    const int fw = min(s_ih[1][NSAMP - 1] - xlo + 1, MAXF);
    const int x0    = xlo & ~3;               // align-down for float4 loads
    const int xext  = (xlo - x0) + fw;        // <= 28
    const int nseg  = (xext + 3) >> 2;        // <= 7, block-uniform
    const int rstr  = nseg << 2;              // LDS row stride (mult of 4)

    // ---- stage: one round trip. thread = (c, row); <=7 float4 each ----
    {
        const int c  = tid & (CCH - 1);
        const int ys = tid >> 3;              // 0..31, active if < fh
        const bool act = ys < fh;
        const float* g =
            feat + ((size_t)(b * CH + c0 + c) * FH + (ylo + ys)) * FW + x0;
        float4 v[MAXSEG];
        #pragma unroll
        for (int s = 0; s < MAXSEG; s++) {
            if (act && s < nseg)              // all issue before any use
                v[s] = *(const float4*)(g + 4 * s);
        }
        float* l = tile + c * PLSTR + ys * rstr;
        #pragma unroll
        for (int s = 0; s < MAXSEG; s++) {
            if (act && s < nseg)
                *(float4*)(l + 4 * s) = v[s];
        }
    }
    __syncthreads();

    // ---- compute: thread = (channel cl, bin slot) ----
    const int cl   = tid & (CCH - 1);
    const int slot = tid >> 3;                // 0..31
    const float* tc = tile + cl * PLSTR;

    for (int bin = slot; bin < OH * OW; bin += BLK / CCH) {
        const int ph = bin / OW;
        const int pw = bin - ph * OW;
        float acc = 0.0f;
        #pragma unroll
        for (int sy = 0; sy < 2; sy++) {
            const int gy = ph * 2 + sy;
            const int rowl = (s_il[0][gy] - ylo) * rstr;
            const int rowh = (s_ih[0][gy] - ylo) * rstr;
            const float wy0 = s_w0[0][gy];
            const float wy1 = s_w1[0][gy];
            #pragma unroll
            for (int sx = 0; sx < 2; sx++) {
                const int gx = pw * 2 + sx;
                const int ixl = s_il[1][gx] - x0;
                const int ixh = s_ih[1][gx] - x0;
                const float wx0 = s_w0[1][gx];
                const float wx1 = s_w1[1][gx];
                acc += wy0 * (wx0 * tc[rowl + ixl] + wx1 * tc[rowl + ixh])
                     + wy1 * (wx0 * tc[rowh + ixl] + wx1 * tc[rowh + ixh]);
            }
        }
        out[(size_t)(r * CH + c0 + cl) * (OH * OW) + bin] = acc * 0.25f;
    }
}

extern "C" void kernel_launch(void* const* d_in, const int* in_sizes, int n_in,
                              void* d_out, int out_size, void* d_ws, size_t ws_size,
                              hipStream_t stream) {
    const float* feat = (const float*)d_in[0];
    const float* rois = (const float*)d_in[1];
    float* out = (float*)d_out;
    roialign_fwd<<<NR * NCHUNK, BLK, 0, stream>>>(feat, rois, out);
}

// Round 3
// 246.473 us; speedup vs baseline: 1.3435x; 1.3435x over previous
//
#include <hip/hip_runtime.h>

// RoIAlign forward, MI355X.
// Shapes: features (4,256,200,200) fp32 NCHW, rois (512,5) fp32,
// out (512,256,7,7) fp32. OUT 7x7, sampling S=2, scale 0.25.
//
// Round-3: direct global->LDS staging (__builtin_amdgcn_global_load_lds,
// width 16). Round 2's register-staged batch spilled to scratch
// (VGPR=36, WRITE_SIZE 163MB) and regressed; direct-to-LDS makes spill
// impossible and keeps every staging load async in flight until the
// single vmcnt(0) the compiler emits at __syncthreads().
//
//  - block = (roi, 8-channel chunk); grid 512*32, 256 threads.
//  - Footprint bound: roi_w = max((x2-x1)*0.25,1) <= 24 feat px; sample
//    span = (13.5/14)*roi_w... precisely 6.75/7*roi_w <= 23.15; fw <= 25.
//    x aligned down to mult of 4 -> x-extent <= 28 -> nseg <= 7 segments
//    of 16B per row; slots per plane tot = fh*nseg <= 175.
//  - Staging: each wave stages 2 channel planes, 3 global_load_lds per
//    plane (3*64 lanes >= 175 slots). Slot s = t*64+lane -> LDS offset
//    s*16B: linear in lane order == the HW's wave-uniform-base + lane*16
//    write pattern (m104). Global src = per-lane aligned float4 row
//    segment (coalesced 16B/lane).
//  - LDS planes padded to stride pstr dwords, pstr ≡ 4 (mod 32), so the
//    8 compute cl-lanes read 8 distinct banks. Pad is between planes only;
//    within-plane layout stays linear for the staging writes.
//  - OOB armor: last segment of the last row of the very last plane can
//    read <=12B past the tensor. Clamp g to end-16B; the clamp can only
//    trigger for a segment whose columns are all >=200 (x0 mult of 4, so
//    base col of a clamping segment is exactly 200 > xhi<=199), i.e. data
//    compute never reads.
//  - Compute: thread = (cl = tid&7, slot = tid>>3); bins slot, slot+32.

#define OH 7
#define OW 7
#define NSAMP 14          // OH*2 == OW*2
#define NB 4
#define CH 256
#define FH 200
#define FW 200
#define NR 512
#define CCH 8             // channels per chunk
#define NCHUNK (CH / CCH) // 32
#define MAXF 25           // max footprint extent (proven bound)
#define MAXSEG 7          // max 16B segments per row (extent<=28)
#define MAXTOTP 177       // max padded slots/plane: 175 -> 177 (≡1 mod 8)
#define BLK 256

__global__ __launch_bounds__(BLK) void roialign_fwd(
    const float* __restrict__ feat,
    const float* __restrict__ rois,
    float* __restrict__ out)
{
    __shared__ float tile[CCH * MAXTOTP * 4];  // 22.7 KB channel planes
    __shared__ int   s_il[2][NSAMP];           // axis 0 = y, 1 = x
    __shared__ int   s_ih[2][NSAMP];
    __shared__ float s_w0[2][NSAMP];
    __shared__ float s_w1[2][NSAMP];

    const int block = blockIdx.x;
    const int r     = block >> 5;              // roi index
    const int chunk = block & (NCHUNK - 1);
    const int c0    = chunk * CCH;
    const int tid   = threadIdx.x;

    // ---- ROI params (wave-uniform scalar loads) ----
    const int   b  = (int)rois[r * 5 + 0];
    const float x1 = rois[r * 5 + 1] * 0.25f;
    const float y1 = rois[r * 5 + 2] * 0.25f;
    const float x2 = rois[r * 5 + 3] * 0.25f;
    const float y2 = rois[r * 5 + 4] * 0.25f;
    const float roi_w = fmaxf(x2 - x1, 1.0f);
    const float roi_h = fmaxf(y2 - y1, 1.0f);
    const float bw = roi_w * (1.0f / OW);
    const float bh = roi_h * (1.0f / OH);

    // ---- per-axis sample metadata (matches reference _axis_weights) ----
    if (tid < 2 * NSAMP) {
        const int axis = tid >= NSAMP;         // 0 = y, 1 = x
        const int i    = tid - axis * NSAMP;
        const float start = axis ? x1 : y1;
        const float bsz   = axis ? bw : bh;
        const float pos   = start + (i + 0.5f) * 0.5f * bsz;
        const float valid = (pos >= -1.0f && pos <= 200.0f) ? 1.0f : 0.0f;
        const float pc    = fminf(fmaxf(pos, 0.0f), 199.0f);
        const int   il    = (int)floorf(pc);
        const int   ih    = min(il + 1, 199);
        const float l     = pc - (float)il;
        s_il[axis][i] = il;
        s_ih[axis][i] = ih;
        s_w0[axis][i] = (1.0f - l) * valid;
        s_w1[axis][i] = l * valid;
    }
    __syncthreads();

    // footprint bounds (sample coords monotone in i)
    const int ylo = s_il[0][0];
    const int xlo = s_il[1][0];
    const int fh = min(s_ih[0][NSAMP - 1] - ylo + 1, MAXF);
    const int fw = min(s_ih[1][NSAMP - 1] - xlo + 1, MAXF);
    const int x0   = xlo & ~3;                 // align-down for 16B loads
    const int nseg = ((xlo - x0) + fw + 3) >> 2;   // <= 7, block-uniform
    const int rstr = nseg << 2;                // LDS dwords per row
    const int tot  = fh * nseg;                // 16B slots per plane <=175
    const int totp = tot + ((1 - tot) & 7);    // pad: totp ≡ 1 (mod 8)
    const int pstr = totp << 2;                // plane stride dwords ≡4 mod 32

    // ---- stage: all loads async direct to LDS, one drain at barrier ----
    {
        const int lane = tid & 63;
        const int wave = tid >> 6;             // 0..3
        const float* gend = feat + (size_t)NB * CH * FH * FW - 4;
        #pragma unroll
        for (int k = 0; k < 2; k++) {
            const int c = (wave << 1) | k;
            const float* gplane =
                feat + ((size_t)(b * CH + c0 + c) * FH + ylo) * FW + x0;
            float* lplane = tile + c * pstr;
            #pragma unroll
            for (int t = 0; t < 3; t++) {      // 3*64 = 192 >= tot
                const int s = (t << 6) + lane;
                if (s < tot) {
                    const int ys = (unsigned)s / (unsigned)nseg;
                    const int sx = s - ys * nseg;
                    const float* g = gplane + ys * FW + (sx << 2);
                    if (g > gend) g = gend;    // OOB armor (see header)
                    float* l = lplane + (s << 2);
                    __builtin_amdgcn_global_load_lds(
                        (const __attribute__((address_space(1))) void*)g,
                        (__attribute__((address_space(3))) void*)l,
                        16, 0, 0);
                }
            }
        }
    }
    __syncthreads();   // compiler emits s_waitcnt vmcnt(0) before barrier

    // ---- compute: thread = (channel cl, bin slot) ----
    const int cl   = tid & (CCH - 1);
    const int slot = tid >> 3;                 // 0..31
    const float* tc = tile + cl * pstr;

    for (int bin = slot; bin < OH * OW; bin += BLK / CCH) {
        const int ph = bin / OW;
        const int pw = bin - ph * OW;
        float acc = 0.0f;
        #pragma unroll
        for (int sy = 0; sy < 2; sy++) {
            const int gy = ph * 2 + sy;
            const int rowl = (s_il[0][gy] - ylo) * rstr;
            const int rowh = (s_ih[0][gy] - ylo) * rstr;
            const float wy0 = s_w0[0][gy];
            const float wy1 = s_w1[0][gy];
            #pragma unroll
            for (int sx = 0; sx < 2; sx++) {
                const int gx = pw * 2 + sx;
                const int ixl = s_il[1][gx] - x0;
                const int ixh = s_ih[1][gx] - x0;
                const float wx0 = s_w0[1][gx];
                const float wx1 = s_w1[1][gx];
                acc += wy0 * (wx0 * tc[rowl + ixl] + wx1 * tc[rowl + ixh])
                     + wy1 * (wx0 * tc[rowh + ixl] + wx1 * tc[rowh + ixh]);
            }
        }
        out[(size_t)(r * CH + c0 + cl) * (OH * OW) + bin] = acc * 0.25f;
    }
}

extern "C" void kernel_launch(void* const* d_in, const int* in_sizes, int n_in,
                              void* d_out, int out_size, void* d_ws, size_t ws_size,
                              hipStream_t stream) {
    const float* feat = (const float*)d_in[0];
    const float* rois = (const float*)d_in[1];
    float* out = (float*)d_out;
    roialign_fwd<<<NR * NCHUNK, BLK, 0, stream>>>(feat, rois, out);
}

// Round 4
// 242.290 us; speedup vs baseline: 1.3667x; 1.0173x over previous
//
#include <hip/hip_runtime.h>

// RoIAlign forward, MI355X.
// Shapes: features (4,256,200,200) fp32 NCHW, rois (512,5) fp32,
// out (512,256,7,7) fp32. OUT 7x7, sampling S=2, scale 0.25.
//
// Round-4: DRAM-locality attack. Rounds 0/1/3 all plateau at ~76-99us with
// FETCH_SIZE ~= unique-line minimum (144MB) but only ~2TB/s achieved on the
// miss stream: the limiter is DRAM row locality of scattered 128B misses,
// not in-flight depth (occupancy 2.3x and async batching were ~neutral).
// Fix = make the miss stream sweep instead of hop:
//  1) chunk-major work order: concurrent blocks read the same 8-ch 5MB slab.
//  2) roi_sort pre-kernel: bitonic sort of 512 rois by (b, y, x) -> perm in
//     d_ws; within a slab the miss stream sweeps the plane monotonically and
//     overlapping rois hit L2 while lines are hot.
//  3) XCD-chunked swizzle (16384%8==0, bijective): each XCD sweeps its own
//     4 slabs; a ~4MB slab fits the per-XCD 4MB L2.
// Staging/compute semantics identical to round 3 (direct global->LDS,
// width-16 async, one vmcnt drain per block), but rows are fixed 8 slots
// (ys=s>>3, sx=s&7, 128B row stride -> LDS dst still linear base+lane*16)
// which deletes the runtime s/nseg division.
//
// Footprint bound: roi_w = max((x2-x1)*0.25,1) <= 24 feat px; sample span
// (13.5-0.5)/14... = 6.75/7*roi_w <= 23.15; fw,fh <= 25. x0 = xlo&~3 ->
// x-extent <= 28 -> nseg <= 7 16B segs/row. col_start = x0+4*sx is a mult
// of 4, so a segment either ends at col<=199 (in-row), wraps into the next
// row (in-bounds), or starts exactly at col 200 (never read by compute);
// the only possible past-tensor read is the final plane's tail, clamped to
// gend (garbage lands only in col>=200 slots, which compute never reads).

#define OH 7
#define OW 7
#define NSAMP 14          // OH*2 == OW*2
#define NB 4
#define CH 256
#define FH 200
#define FW 200
#define NR 512
#define CCH 8             // channels per chunk
#define NCHUNK (CH / CCH) // 32
#define MAXF 25           // max footprint extent (proven bound)
#define PSTRMAX (MAXF * 32 + 4)
#define BLK 256

// ---- pre-kernel: bitonic sort of roi indices by (batch, y, x) ----
__global__ __launch_bounds__(NR) void roi_sort(
    const float* __restrict__ rois, int* __restrict__ perm)
{
    __shared__ unsigned key[NR];
    const int t = threadIdx.x;
    {
        const int   b  = (int)rois[t * 5 + 0];
        const float x1 = rois[t * 5 + 1] * 0.25f;
        const float y1 = rois[t * 5 + 2] * 0.25f;
        const int qy = min(255, max(0, (int)y1));
        const int qx = min(255, max(0, (int)x1));
        key[t] = ((unsigned)b << 27) | ((unsigned)qy << 18)
               | ((unsigned)qx << 9) | (unsigned)t;   // low 9 bits: roi id
    }
    for (int k = 2; k <= NR; k <<= 1) {
        for (int j = k >> 1; j > 0; j >>= 1) {
            __syncthreads();
            const int ixj = t ^ j;
            if (ixj > t) {
                const unsigned a = key[t], c = key[ixj];
                const bool asc = ((t & k) == 0);
                if ((a > c) == asc) { key[t] = c; key[ixj] = a; }
            }
        }
    }
    __syncthreads();
    perm[t] = (int)(key[t] & (NR - 1u));
}

__global__ __launch_bounds__(BLK) void roialign_fwd(
    const float* __restrict__ feat,
    const float* __restrict__ rois,
    const int*   __restrict__ perm,
    float* __restrict__ out)
{
    __shared__ float tile[CCH * PSTRMAX];      // 25.7 KB channel planes
    __shared__ int   s_il[2][NSAMP];           // axis 0 = y, 1 = x
    __shared__ int   s_ih[2][NSAMP];
    __shared__ float s_w0[2][NSAMP];
    __shared__ float s_w1[2][NSAMP];

    // XCD-chunked swizzle + chunk-major decode:
    // XCD k executes works k*2048 .. k*2048+2047 in sequential order.
    const int bid   = blockIdx.x;
    const int nid   = ((bid & 7) << 11) | (bid >> 3);
    const int chunk = nid >> 9;                // 0..31 (slab-major)
    const int r     = perm[nid & (NR - 1)];    // sorted roi order
    const int c0    = chunk * CCH;
    const int tid   = threadIdx.x;

    // ---- ROI params (wave-uniform scalar loads) ----
    const int   b  = (int)rois[r * 5 + 0];
    const float x1 = rois[r * 5 + 1] * 0.25f;
    const float y1 = rois[r * 5 + 2] * 0.25f;
    const float x2 = rois[r * 5 + 3] * 0.25f;
    const float y2 = rois[r * 5 + 4] * 0.25f;
    const float roi_w = fmaxf(x2 - x1, 1.0f);
    const float roi_h = fmaxf(y2 - y1, 1.0f);
    const float bw = roi_w * (1.0f / OW);
    const float bh = roi_h * (1.0f / OH);

    // ---- per-axis sample metadata (matches reference _axis_weights) ----
    if (tid < 2 * NSAMP) {
        const int axis = tid >= NSAMP;         // 0 = y, 1 = x
        const int i    = tid - axis * NSAMP;
        const float start = axis ? x1 : y1;
        const float bsz   = axis ? bw : bh;
        const float pos   = start + (i + 0.5f) * 0.5f * bsz;
        const float valid = (pos >= -1.0f && pos <= 200.0f) ? 1.0f : 0.0f;
        const float pc    = fminf(fmaxf(pos, 0.0f), 199.0f);
        const int   il    = (int)floorf(pc);
        const int   ih    = min(il + 1, 199);
        const float l     = pc - (float)il;
        s_il[axis][i] = il;
        s_ih[axis][i] = ih;
        s_w0[axis][i] = (1.0f - l) * valid;
        s_w1[axis][i] = l * valid;
    }
    __syncthreads();

    // footprint bounds (sample coords monotone in i)
    const int ylo = s_il[0][0];
    const int xlo = s_il[1][0];
    const int fh = min(s_ih[0][NSAMP - 1] - ylo + 1, MAXF);
    const int fw = min(s_ih[1][NSAMP - 1] - xlo + 1, MAXF);
    const int x0   = xlo & ~3;                 // align-down for 16B loads
    const int nseg = ((xlo - x0) + fw + 3) >> 2;   // <= 7, block-uniform
    const int pstr = (fh << 5) + 4;            // plane stride dw, ≡4 mod 32

    // ---- stage: all loads async direct to LDS, one drain at barrier.
    // Fixed 8-slot rows: slot s -> (ys = s>>3, sx = s&7); LDS dst = plane +
    // s*16B (row stride 8*16 = 128B) => wave-uniform base + lane*16. ----
    {
        const int lane = tid & 63;
        const int wave = tid >> 6;             // 0..3
        const float* gend = feat + (size_t)NB * CH * FH * FW - 4;
        #pragma unroll
        for (int k = 0; k < 2; k++) {
            const int c = (wave << 1) | k;
            const float* gplane =
                feat + ((size_t)(b * CH + c0 + c) * FH + ylo) * FW + x0;
            float* lplane = tile + c * pstr;
            #pragma unroll
            for (int t = 0; t < 4; t++) {      // rows t*8..t*8+7
                const int s  = (t << 6) + lane;
                const int ys = s >> 3;
                const int sx = s & 7;
                if (ys < fh && sx < nseg) {
                    const float* g = gplane + ys * FW + (sx << 2);
                    if (g > gend) g = gend;    // OOB armor (see header)
                    __builtin_amdgcn_global_load_lds(
                        (const __attribute__((address_space(1))) void*)g,
                        (__attribute__((address_space(3))) void*)(lplane + (s << 2)),
                        16, 0, 0);
                }
            }
        }
    }
    __syncthreads();   // compiler emits s_waitcnt vmcnt(0) before barrier

    // ---- compute: thread = (channel cl, bin slot) ----
    const int cl   = tid & (CCH - 1);
    const int slot = tid >> 3;                 // 0..31
    const float* tc = tile + cl * pstr;

    for (int bin = slot; bin < OH * OW; bin += BLK / CCH) {
        const int ph = bin / OW;
        const int pw = bin - ph * OW;
        float acc = 0.0f;
        #pragma unroll
        for (int sy = 0; sy < 2; sy++) {
            const int gy = ph * 2 + sy;
            const int rowl = (s_il[0][gy] - ylo) << 5;
            const int rowh = (s_ih[0][gy] - ylo) << 5;
            const float wy0 = s_w0[0][gy];
            const float wy1 = s_w1[0][gy];
            #pragma unroll
            for (int sx = 0; sx < 2; sx++) {
                const int gx = pw * 2 + sx;
                const int ixl = s_il[1][gx] - x0;
                const int ixh = s_ih[1][gx] - x0;
                const float wx0 = s_w0[1][gx];
                const float wx1 = s_w1[1][gx];
                acc += wy0 * (wx0 * tc[rowl + ixl] + wx1 * tc[rowl + ixh])
                     + wy1 * (wx0 * tc[rowh + ixl] + wx1 * tc[rowh + ixh]);
            }
        }
        out[(size_t)(r * CH + c0 + cl) * (OH * OW) + bin] = acc * 0.25f;
    }
}

extern "C" void kernel_launch(void* const* d_in, const int* in_sizes, int n_in,
                              void* d_out, int out_size, void* d_ws, size_t ws_size,
                              hipStream_t stream) {
    const float* feat = (const float*)d_in[0];
    const float* rois = (const float*)d_in[1];
    float* out = (float*)d_out;
    int* perm = (int*)d_ws;
    roi_sort<<<1, NR, 0, stream>>>(rois, perm);
    roialign_fwd<<<NR * NCHUNK, BLK, 0, stream>>>(feat, rois, perm, out);
}